// Round 6
// baseline (25.808 us; speedup 1.0000x reference)
//
#include <hip/hip_runtime.h>

// S=8192, H=2048
// v = W^T h;  energies[s] = enc[s,:] . v  (+b.h softmax-invariant, dropped)
// out = softmax(energies)
// ws floats: v[2048] | e[8192] | pairs[2*2048]

#define Hdim 2048
#define Sdim 8192
#define NBLK2 2048  // k2 grid

__global__ void kv_matvec(const float* __restrict__ W, const float* __restrict__ hid,
                          float* __restrict__ v) {
    // 256 blocks x 512 thr. Block owns 8 cols, all 2048 rows.
    // XCD-contiguous column ownership (b&7 = XCD round-robin assumption).
    int b = blockIdx.x;
    int c0 = (b & 7) * 256 + (b >> 3) * 8;
    int t = threadIdx.x;
    int cp = (t & 1) * 4;
    int rl = t >> 1;
    float4 acc = {0.f, 0.f, 0.f, 0.f};
#pragma unroll
    for (int i = 0; i < 8; ++i) {
        int k = rl + 256 * i;
        float hk = hid[k];
        float4 w = *reinterpret_cast<const float4*>(W + (size_t)k * Hdim + c0 + cp);
        acc.x += w.x * hk;
        acc.y += w.y * hk;
        acc.z += w.z * hk;
        acc.w += w.w * hk;
    }
    __shared__ float4 red[512];
    red[t] = acc;
    __syncthreads();
    for (int s = 128; s > 0; s >>= 1) {
        if (rl < s) {
            float4 o = red[t + 2 * s];
            float4 m = red[t];
            m.x += o.x; m.y += o.y; m.z += o.z; m.w += o.w;
            red[t] = m;
        }
        __syncthreads();
    }
    if (t < 2) *reinterpret_cast<float4*>(v + c0 + t * 4) = red[t];
}

__global__ void k2_energies(const float* __restrict__ enc, const float* __restrict__ v,
                            float* __restrict__ e, float2* __restrict__ pairs) {
    // 2048 blocks x 256 thr; 4 waves/block, one enc row per wave.
    // Also emits per-block online-softmax pair (max, sumexp) over its 4 energies.
    int t = threadIdx.x;
    int lane = t & 63;
    int wave = t >> 6;
    int s = blockIdx.x * 4 + wave;
    const float* row = enc + (size_t)s * Hdim;
    float acc = 0.f;
#pragma unroll
    for (int i = 0; i < 8; ++i) {
        int idx = i * 256 + lane * 4;
        float4 a = *reinterpret_cast<const float4*>(row + idx);
        float4 w = *reinterpret_cast<const float4*>(v + idx);
        acc += a.x * w.x + a.y * w.y + a.z * w.z + a.w * w.w;
    }
#pragma unroll
    for (int off = 32; off > 0; off >>= 1) acc += __shfl_xor(acc, off, 64);
    __shared__ float se[4];
    if (lane == 0) {
        e[s] = acc;
        se[wave] = acc;
    }
    __syncthreads();
    if (t == 0) {
        float m = fmaxf(fmaxf(se[0], se[1]), fmaxf(se[2], se[3]));
        float l = __expf(se[0] - m) + __expf(se[1] - m) + __expf(se[2] - m) + __expf(se[3] - m);
        pairs[blockIdx.x] = make_float2(m, l);
    }
}

__global__ void k3_norm(const float* __restrict__ e, const float2* __restrict__ pairs,
                        float* __restrict__ out) {
    // 32 blocks x 256 thr. Each block redundantly reduces all 2048 (m,l) pairs
    // (deterministic: same order in every block), then normalizes its 256 outputs.
    int t = threadIdx.x;
    int lane = t & 63, wave = t >> 6;
    float m = -1e30f;
    float2 p[8];
#pragma unroll
    for (int j = 0; j < 8; ++j) {
        p[j] = pairs[t + 256 * j];
        m = fmaxf(m, p[j].x);
    }
#pragma unroll
    for (int off = 32; off > 0; off >>= 1) m = fmaxf(m, __shfl_xor(m, off, 64));
    __shared__ float red[4];
    __shared__ float bcastM, bcastL;
    if (lane == 0) red[wave] = m;
    __syncthreads();
    if (t == 0) bcastM = fmaxf(fmaxf(red[0], red[1]), fmaxf(red[2], red[3]));
    __syncthreads();
    float M = bcastM;
    float l = 0.f;
#pragma unroll
    for (int j = 0; j < 8; ++j) l += p[j].y * __expf(p[j].x - M);
#pragma unroll
    for (int off = 32; off > 0; off >>= 1) l += __shfl_xor(l, off, 64);
    __syncthreads();
    if (lane == 0) red[wave] = l;
    __syncthreads();
    if (t == 0) bcastL = red[0] + red[1] + red[2] + red[3];
    __syncthreads();
    float invL = 1.0f / bcastL;
    int idx = blockIdx.x * 256 + t;
    out[idx] = __expf(e[idx] - M) * invL;
}

extern "C" void kernel_launch(void* const* d_in, const int* in_sizes, int n_in,
                              void* d_out, int out_size, void* d_ws, size_t ws_size,
                              hipStream_t stream) {
    const float* hid = (const float*)d_in[0];   // (1, H)
    const float* enc = (const float*)d_in[1];   // (S, 1, H)
    const float* W   = (const float*)d_in[2];   // (H, H)
    // d_in[3] = b : dropped (softmax shift-invariant)
    float* out = (float*)d_out;                 // S floats
    float* ws = (float*)d_ws;

    float* v = ws;                        // 2048
    float* e = v + Hdim;                  // 8192
    float2* pairs = (float2*)(e + Sdim);  // 2048 float2

    kv_matvec<<<256, 512, 0, stream>>>(W, hid, v);
    k2_energies<<<NBLK2, 256, 0, stream>>>(enc, v, e, pairs);
    k3_norm<<<32, 256, 0, stream>>>(e, pairs, out);
}